// Round 12
// baseline (526.792 us; speedup 1.0000x reference)
//
#include <hip/hip_runtime.h>
#include <hip/hip_bf16.h>

typedef __attribute__((ext_vector_type(8))) short short8;
typedef __attribute__((ext_vector_type(4))) short bfx4;
typedef __attribute__((ext_vector_type(4))) float floatx4;

#define SEQ     2048
#define DMODEL  768
#define DINNER  1536
#define DSTATE  128
#define NH      24
#define CONVDIM 1792
#define NPROJ   3352   // 2*DINNER + 2*DSTATE + NH
#define QCH     64     // SSD chunk length
#define NCH     (SEQ / QCH)   // 32 chunks

__device__ inline float bf2f(short s) {
    return __uint_as_float(((unsigned)(unsigned short)s) << 16);
}
__device__ inline short f2bf(float f) {
    __hip_bfloat16 h = __float2bfloat16(f);
    return *reinterpret_cast<short*>(&h);
}
__device__ inline void gl_lds16(const void* g, void* l) {
    __builtin_amdgcn_global_load_lds((const __attribute__((address_space(1))) unsigned int*)g,
                                     (__attribute__((address_space(3))) unsigned int*)l, 16, 0, 0);
}

// ---------------------------------------------------------------- converts (float4)
__global__ __launch_bounds__(256) void cvt_kernel(const float* __restrict__ src,
                                                  __hip_bfloat16* __restrict__ dst, int n4) {
    int i = blockIdx.x * 256 + threadIdx.x;
    if (i >= n4) return;
    float4 v = *(const float4*)(src + (size_t)i * 4);
    bfx4 o = { f2bf(v.x), f2bf(v.y), f2bf(v.z), f2bf(v.w) };
    *(bfx4*)((short*)dst + (size_t)i * 4) = o;
}

// ---------------------------------------------------------------- GEMM 128x128, BK=32, double-buffered
// (R11 structure — at its plateau; unchanged)
__global__ __launch_bounds__(256) void gemm_bt(const __hip_bfloat16* __restrict__ Abase, size_t aStride,
                                               const __hip_bfloat16* __restrict__ Bbase, size_t bStride,
                                               float* __restrict__ C,
                                               __hip_bfloat16* __restrict__ Zb,
                                               __hip_bfloat16* __restrict__ Xb,
                                               float* __restrict__ DT,
                                               float* __restrict__ LA,
                                               const float* __restrict__ dtbias,
                                               const float* __restrict__ Alog,
                                               int M, int N, int K, int zdiv, int mode, int flipA) {
    __shared__ short As[2][64 * 64];
    __shared__ short Bs[2][64 * 64];
    int tid = threadIdx.x;
    int w = tid >> 6, lane = tid & 63;
    int q = lane >> 4, mm = lane & 15;
    int wm = w >> 1, wn = w & 1;
    int m0 = blockIdx.x * 128, n0 = blockIdx.y * 128;
    int z = blockIdx.z;
    int dir = z / zdiv, ks = z - dir * zdiv;
    int kl = K / zdiv;
    int kbeg = ks * kl;
    const short* Ag = (const short*)Abase + (size_t)dir * aStride;
    const short* Bg = (const short*)Bbase + (size_t)dir * bStride;
    int fA = flipA && dir;

    size_t aoff[2], boff[2];
    int ldso[2];
#pragma unroll
    for (int j = 0; j < 2; j++) {
        int widx = w * 2 + j;
        int ln = widx * 8 + (lane >> 3);
        int s  = lane & 7;
        int c  = s ^ (ln & 7);
        int row = (c < 4) ? ln : ln + 64;
        int ch  = (c < 4) ? c : (c ^ 4);
        int ar = m0 + row;
        if (fA) { int bb = ar >> 11, tt = ar & 2047; ar = (bb << 11) + (2047 - tt); }
        aoff[j] = (size_t)ar * K + ch * 8;
        int br = n0 + row; if (br > N - 1) br = N - 1;
        boff[j] = (size_t)br * K + ch * 8;
        ldso[j] = widx * 1024;
    }

    floatx4 acc[16];
#pragma unroll
    for (int i = 0; i < 16; i++) acc[i] = (floatx4){0.f, 0.f, 0.f, 0.f};

    int niter = kl / 32;
    auto stage = [&](int buf, int k0) {
#pragma unroll
        for (int j = 0; j < 2; j++) {
            gl_lds16(Ag + aoff[j] + kbeg + k0, (char*)&As[buf][0] + ldso[j]);
            gl_lds16(Bg + boff[j] + kbeg + k0, (char*)&Bs[buf][0] + ldso[j]);
        }
    };
    stage(0, 0);
    int slotA = (q ^ (mm & 7) ^ (wm << 2)) * 8;
    int slotB = (q ^ (mm & 7) ^ (wn << 2)) * 8;
    for (int it = 0; it < niter; it++) {
        __syncthreads();
        if (it + 1 < niter) stage((it + 1) & 1, (it + 1) * 32);
        const short* Ab = &As[it & 1][0];
        const short* Bb = &Bs[it & 1][0];
        short8 af[4], bfr[4];
#pragma unroll
        for (int mb = 0; mb < 4; mb++)
            af[mb] = *(const short8*)&Ab[(mb * 16 + mm) * 64 + slotA];
#pragma unroll
        for (int nb = 0; nb < 4; nb++)
            bfr[nb] = *(const short8*)&Bb[(nb * 16 + mm) * 64 + slotB];
#pragma unroll
        for (int mb = 0; mb < 4; mb++)
#pragma unroll
            for (int nb = 0; nb < 4; nb++)
                acc[mb * 4 + nb] = __builtin_amdgcn_mfma_f32_16x16x32_bf16(af[mb], bfr[nb], acc[mb * 4 + nb], 0, 0, 0);
    }

    __hip_bfloat16* Zb2 = Zb + (size_t)dir * 4096 * DINNER;
    __hip_bfloat16* Xb2 = Xb + (size_t)dir * 4096 * CONVDIM;
    float* DT2 = DT + (size_t)dir * 4096 * NH;
    float* LA2 = LA + (size_t)dir * 4096 * NH;
    const float* dtb2 = dtbias + dir * NH;
    const float* Al2  = Alog + dir * NH;

#pragma unroll
    for (int mb = 0; mb < 4; mb++) {
#pragma unroll
        for (int nb = 0; nb < 4; nb++) {
            int col = n0 + wn * 64 + nb * 16 + mm;
            if (col >= N) continue;
#pragma unroll
            for (int r = 0; r < 4; r++) {
                int rr = m0 + wm * 64 + mb * 16 + q * 4 + r;
                float v = acc[mb * 4 + nb][r];
                if (mode == 1) {
                    int orow = rr;
                    if (dir) { int b = rr >> 11, t = rr & 2047; orow = (b << 11) + (2047 - t); }
                    atomicAdd(&C[(size_t)orow * N + col], v);
                } else {
                    if (col < DINNER) {
                        Zb2[(size_t)rr * DINNER + col] = __float2bfloat16(v);
                    } else if (col < DINNER + CONVDIM) {
                        Xb2[(size_t)rr * CONVDIM + (col - DINNER)] = __float2bfloat16(v);
                    } else {
                        int hh = col - (DINNER + CONVDIM);
                        float raw = v + dtb2[hh];
                        float dtv = (raw > 20.f) ? raw : log1pf(__expf(raw));
                        float Av  = -__expf(Al2[hh]);
                        DT2[(size_t)rr * NH + hh] = dtv;
                        LA2[(size_t)rr * NH + hh] = dtv * Av;
                    }
                }
            }
        }
    }
}

// ---------------------------------------------------------------- conv (depthwise K=4) + silu
__global__ __launch_bounds__(256) void conv_kernel(const __hip_bfloat16* __restrict__ Xb,
                                                   const float* __restrict__ conv_w,
                                                   const float* __restrict__ conv_b,
                                                   __hip_bfloat16* __restrict__ xh,
                                                   __hip_bfloat16* __restrict__ Bm,
                                                   __hip_bfloat16* __restrict__ Cm) {
    int db  = blockIdx.x >> 7;
    int dir = db >> 1;
    int t0  = (blockIdx.x & 127) * 16;
    int c8  = threadIdx.x * 8;
    if (c8 >= CONVDIM) return;

    float wk[4][8], bs[8];
#pragma unroll
    for (int j = 0; j < 8; j++) {
        bs[j] = conv_b[dir * CONVDIM + c8 + j];
#pragma unroll
        for (int k = 0; k < 4; k++) wk[k][j] = conv_w[((size_t)dir * CONVDIM + c8 + j) * 4 + k];
    }

    const short* xrow = (const short*)Xb + (size_t)db * SEQ * CONVDIM + c8;
    short8 win[4];
    const short8 zer = {0, 0, 0, 0, 0, 0, 0, 0};
#pragma unroll
    for (int k = 0; k < 3; k++) {
        int ts = t0 - 3 + k;
        win[k] = (ts >= 0) ? *(const short8*)(xrow + (size_t)ts * CONVDIM) : zer;
    }

    for (int tt = 0; tt < 16; tt++) {
        int t = t0 + tt;
        win[3] = *(const short8*)(xrow + (size_t)t * CONVDIM);
        short8 outv;
#pragma unroll
        for (int j = 0; j < 8; j++) {
            float acc = bs[j];
#pragma unroll
            for (int k = 0; k < 4; k++) acc += wk[k][j] * bf2f(win[k][j]);
            float sv = acc / (1.f + __expf(-acc));
            outv[j] = f2bf(sv);
        }
        if (c8 < DINNER)
            *(short8*)((short*)xh + (size_t)(db * SEQ + t) * DINNER + c8) = outv;
        else if (c8 < DINNER + DSTATE)
            *(short8*)((short*)Bm + (size_t)(db * SEQ + t) * DSTATE + (c8 - DINNER)) = outv;
        else
            *(short8*)((short*)Cm + (size_t)(db * SEQ + t) * DSTATE + (c8 - DINNER - DSTATE)) = outv;
        win[0] = win[1]; win[1] = win[2]; win[2] = win[3];
    }
}

// ---------------------------------------------------------------- fused SSD (persistent h in regs)
// block = (dbh, pg): pg = p-quarter (16 p). 384 blocks. Loops 32 chunks serially.
// Per chunk: P=C@B^T (global frags); G=P*decay; S[16p][128n]=Xs@Bt; Y=G@Xu + Ct@Hp^T;
// h = h*W + S (fp32, MFMA C-layout: lane q*4+r = p-row, mm = n-col, wave w owns n-blocks 2w,2w+1).
__global__ __launch_bounds__(256) void ssd_fused(const __hip_bfloat16* __restrict__ XH,
                                                 const __hip_bfloat16* __restrict__ BMh,
                                                 const __hip_bfloat16* __restrict__ CMh,
                                                 const float* __restrict__ DT,
                                                 const float* __restrict__ LA,
                                                 __hip_bfloat16* __restrict__ Yb) {
    int blk = blockIdx.x;
    int pg = blk & 3;
    int dbh = blk >> 2;
    int hh = dbh % NH, db = dbh / NH;
    int pbase = pg * 16;

    __shared__ float cum_s[QCH], dt_s[QCH];
    __shared__ float Wsh;
    __shared__ short Bt[128][72];   // B^T [n][s]
    __shared__ short Ct[64][136];   // exp(cum_t)*C [t][n]
    __shared__ short G[64][72];     // [t][s]
    __shared__ short Xs[16][72];    // scaled X~^T [p][s]
    __shared__ short Xu[16][72];    // unscaled X^T [p][s]
    __shared__ short Hp[16][136];   // h_prev bf16 [p][n]

    int tid = threadIdx.x;
    int lane = tid & 63, w = tid >> 6;
    int q = lane >> 4, mm = lane & 15;

    float h[2][4];
#pragma unroll
    for (int a = 0; a < 2; a++)
#pragma unroll
        for (int r = 0; r < 4; r++) h[a][r] = 0.f;

    for (int ck = 0; ck < NCH; ck++) {
        int base_row = db * SEQ + ck * QCH;
        const short* Cg = (const short*)CMh + (size_t)base_row * DSTATE;
        const short* Bg = (const short*)BMh + (size_t)base_row * DSTATE;

        // ---- cum/dt (wave 0) ----
        if (tid < QCH) {
            float la  = LA[(size_t)(base_row + tid) * NH + hh];
            float dtv = DT[(size_t)(base_row + tid) * NH + hh];
            float cs = la;
#pragma unroll
            for (int d = 1; d < 64; d <<= 1) {
                float u = __shfl_up(cs, d);
                if (tid >= d) cs += u;
            }
            cum_s[tid] = cs;
            dt_s[tid]  = dtv;
            if (tid == QCH - 1) Wsh = __expf(cs);
        }

        // ---- P = C @ B^T (global frags, no LDS dep) ----
        floatx4 P[4];
#pragma unroll
        for (int i = 0; i < 4; i++) P[i] = (floatx4){0.f, 0.f, 0.f, 0.f};
#pragma unroll
        for (int kk = 0; kk < 4; kk++) {
            short8 a = *(const short8*)(Cg + (size_t)(w * 16 + mm) * DSTATE + kk * 32 + q * 8);
#pragma unroll
            for (int cb = 0; cb < 4; cb++) {
                short8 b = *(const short8*)(Bg + (size_t)(cb * 16 + mm) * DSTATE + kk * 32 + q * 8);
                P[cb] = __builtin_amdgcn_mfma_f32_16x16x32_bf16(a, b, P[cb], 0, 0, 0);
            }
        }
        __syncthreads();   // cum_s/dt_s/Wsh visible; prev chunk's MFMA reads done (end-of-loop barrier)

        // ---- builds ----
        // Ct = exp(cum_t) * C : t = tid&63, nb4 = tid>>6 covers 32 n
        {
            int t = tid & 63, nb4 = tid >> 6;
            float wt = __expf(cum_s[t]);
            const short* src = Cg + (size_t)t * DSTATE + nb4 * 32;
#pragma unroll
            for (int u = 0; u < 2; u++) {
                short8 v  = *(const short8*)(src + u * 16);
                short8 v2 = *(const short8*)(src + u * 16 + 8);
#pragma unroll
                for (int j = 0; j < 4; j++) {
                    unsigned lo = (unsigned short)f2bf(wt * bf2f(v[2 * j]));
                    unsigned hi = (unsigned short)f2bf(wt * bf2f(v[2 * j + 1]));
                    *(unsigned*)&Ct[t][nb4 * 32 + u * 16 + 2 * j] = lo | (hi << 16);
                    lo = (unsigned short)f2bf(wt * bf2f(v2[2 * j]));
                    hi = (unsigned short)f2bf(wt * bf2f(v2[2 * j + 1]));
                    *(unsigned*)&Ct[t][nb4 * 32 + u * 16 + 8 + 2 * j] = lo | (hi << 16);
                }
            }
        }
        // Bt = B^T : s2 pairs, nb = tid>>5 covers 16 n
        {
            int s2 = (tid & 31) * 2, nb = tid >> 5;
            const short* r0 = Bg + (size_t)s2 * DSTATE + nb * 16;
            const short* r1 = r0 + DSTATE;
            short8 b0a = *(const short8*)r0,  b0b = *(const short8*)(r0 + 8);
            short8 b1a = *(const short8*)r1,  b1b = *(const short8*)(r1 + 8);
#pragma unroll
            for (int j = 0; j < 8; j++) {
                *(unsigned*)&Bt[nb * 16 + j][s2] =
                    (unsigned)(unsigned short)b0a[j] | ((unsigned)(unsigned short)b1a[j] << 16);
                *(unsigned*)&Bt[nb * 16 + 8 + j][s2] =
                    (unsigned)(unsigned short)b0b[j] | ((unsigned)(unsigned short)b1b[j] << 16);
            }
        }
        // Xu (tid<64) / Xs (tid 64..127): p-slice 16
        if (tid < 128) {
            int s2 = (tid & 31) * 2;
            int pb = (tid >> 5) & 1;
            const short* r0 = (const short*)XH + (size_t)(base_row + s2) * DINNER + hh * 64 + pbase + pb * 8;
            const short* r1 = r0 + DINNER;
            short8 x0 = *(const short8*)r0;
            short8 x1 = *(const short8*)r1;
            if (tid >= 64) {
                float f0 = dt_s[s2]     * __expf(cum_s[QCH - 1] - cum_s[s2]);
                float f1 = dt_s[s2 + 1] * __expf(cum_s[QCH - 1] - cum_s[s2 + 1]);
#pragma unroll
                for (int j = 0; j < 8; j++) {
                    unsigned lo = (unsigned short)f2bf(f0 * bf2f(x0[j]));
                    unsigned hi = (unsigned short)f2bf(f1 * bf2f(x1[j]));
                    *(unsigned*)&Xs[pb * 8 + j][s2] = lo | (hi << 16);
                }
            } else {
#pragma unroll
                for (int j = 0; j < 8; j++) {
                    *(unsigned*)&Xu[pb * 8 + j][s2] =
                        (unsigned)(unsigned short)x0[j] | ((unsigned)(unsigned short)x1[j] << 16);
                }
            }
        }
        // G = P * decay (each wave its own t-rows)
#pragma unroll
        for (int cb = 0; cb < 4; cb++) {
#pragma unroll
            for (int r = 0; r < 4; r++) {
                int t = w * 16 + q * 4 + r;
                int s = cb * 16 + mm;
                float g = (s <= t) ? P[cb][r] * __expf(cum_s[t] - cum_s[s]) * dt_s[s] : 0.f;
                G[t][s] = f2bf(g);
            }
        }
        // Hp = h_prev (bf16), lane owns p-rows q*4+r, n-cols (w*2+a)*16+mm
#pragma unroll
        for (int a = 0; a < 2; a++)
#pragma unroll
            for (int r = 0; r < 4; r++)
                Hp[q * 4 + r][(w * 2 + a) * 16 + mm] = f2bf(h[a][r]);
        __syncthreads();

        // ---- MFMAs ----
        floatx4 Sa[2];
        Sa[0] = (floatx4){0.f, 0.f, 0.f, 0.f};
        Sa[1] = (floatx4){0.f, 0.f, 0.f, 0.f};
#pragma unroll
        for (int kk = 0; kk < 2; kk++) {
            short8 a = *(const short8*)&Xs[mm][kk * 32 + q * 8];
#pragma unroll
            for (int nb2 = 0; nb2 < 2; nb2++) {
                short8 b = *(const short8*)&Bt[(w * 2 + nb2) * 16 + mm][kk * 32 + q * 8];
                Sa[nb2] = __builtin_amdgcn_mfma_f32_16x16x32_bf16(a, b, Sa[nb2], 0, 0, 0);
            }
        }
        floatx4 Y = (floatx4){0.f, 0.f, 0.f, 0.f};
#pragma unroll
        for (int kk = 0; kk < 2; kk++) {
            short8 a = *(const short8*)&G[w * 16 + mm][kk * 32 + q * 8];
            short8 b = *(const short8*)&Xu[mm][kk * 32 + q * 8];
            Y = __builtin_amdgcn_mfma_f32_16x16x32_bf16(a, b, Y, 0, 0, 0);
        }
#pragma unroll
        for (int kk = 0; kk < 4; kk++) {
            short8 a = *(const short8*)&Ct[w * 16 + mm][kk * 32 + q * 8];
            short8 b = *(const short8*)&Hp[mm][kk * 32 + q * 8];
            Y = __builtin_amdgcn_mfma_f32_16x16x32_bf16(a, b, Y, 0, 0, 0);
        }
        // h update (fp32)
        float Wv = Wsh;
#pragma unroll
        for (int a = 0; a < 2; a++)
#pragma unroll
            for (int r = 0; r < 4; r++)
                h[a][r] = fmaf(h[a][r], Wv, Sa[a][r]);
        // Y store
#pragma unroll
        for (int r = 0; r < 4; r++)
            Yb[(size_t)(base_row + w * 16 + q * 4 + r) * DINNER + hh * 64 + pbase + mm] =
                __float2bfloat16(Y[r]);
        __syncthreads();   // protect LDS (incl. Hp) before next chunk's builds
    }
}

// ---------------------------------------------------------------- gating + RMSNorm (192 thr x 8 ch)
__global__ __launch_bounds__(192) void gate_kernel(const __hip_bfloat16* __restrict__ Yb,
                                                   const __hip_bfloat16* __restrict__ xh,
                                                   const __hip_bfloat16* __restrict__ Zb,
                                                   const float* __restrict__ Dp,
                                                   const float* __restrict__ norm_w,
                                                   __hip_bfloat16* __restrict__ A2) {
    int row = blockIdx.x;
    int dir = row >> 12;
    int c8 = threadIdx.x * 8;
    int hd = c8 >> 6;
    const short* yr = (const short*)Yb + (size_t)row * DINNER + c8;
    const short* xr = (const short*)xh + (size_t)row * DINNER + c8;
    const short* zr = (const short*)Zb + (size_t)row * DINNER + c8;

    short8 y8 = *(const short8*)yr;
    short8 x8 = *(const short8*)xr;
    short8 z8 = *(const short8*)zr;
    float Dv = Dp[dir * NH + hd];

    float vals[8];
    float ss = 0.f;
#pragma unroll
    for (int j = 0; j < 8; j++) {
        float v = bf2f(y8[j]) + Dv * bf2f(x8[j]);
        float z = bf2f(z8[j]);
        v *= z / (1.f + __expf(-z));
        vals[j] = v;
        ss += v * v;
    }
#pragma unroll
    for (int off = 32; off; off >>= 1) ss += __shfl_down(ss, off);
    __shared__ float ls[3];
    if ((threadIdx.x & 63) == 0) ls[threadIdx.x >> 6] = ss;
    __syncthreads();
    float tot = ls[0] + ls[1] + ls[2];
    float scale = rsqrtf(tot / (float)DINNER + 1e-5f);

    const float* nw = norm_w + dir * DINNER + c8;
    short8 o;
#pragma unroll
    for (int j = 0; j < 8; j++) o[j] = f2bf(vals[j] * scale * nw[j]);
    *(short8*)((short*)A2 + (size_t)row * DINNER + c8) = o;
}

// ---------------------------------------------------------------- launch
extern "C" void kernel_launch(void* const* d_in, const int* in_sizes, int n_in,
                              void* d_out, int out_size, void* d_ws, size_t ws_size,
                              hipStream_t stream) {
    const float* x        = (const float*)d_in[0];
    const float* in_w     = (const float*)d_in[1];
    const float* conv_w   = (const float*)d_in[2];
    const float* conv_b   = (const float*)d_in[3];
    const float* dt_bias  = (const float*)d_in[4];
    const float* A_log    = (const float*)d_in[5];
    const float* Dp       = (const float*)d_in[6];
    const float* norm_w   = (const float*)d_in[7];
    const float* out_w    = (const float*)d_in[8];
    float* out = (float*)d_out;

    const size_t szW2 = (size_t)2 * DMODEL * DINNER * 2;
    const size_t szZ  = (size_t)8192 * DINNER * 2;
    const size_t szXH = (size_t)8192 * DINNER * 2;
    const size_t szBM = (size_t)8192 * DSTATE * 2;
    const size_t szCM = szBM;
    const size_t szDT = (size_t)8192 * NH * 4;
    const size_t szLA = szDT;
    const size_t szA1 = (size_t)4096 * DMODEL * 2;
    const size_t szW1 = (size_t)2 * NPROJ * DMODEL * 2;
    const size_t szXB = (size_t)8192 * CONVDIM * 2;
    const size_t szYb = (size_t)8192 * DINNER * 2;
    const size_t szRa = szA1 + szW1 + szXB;
    size_t szR = (szRa > szYb) ? szRa : szYb;

    char* ws = (char*)d_ws;
    size_t off = 0;
    auto alloc = [&](size_t bytes) { char* p = ws + off; off += (bytes + 255) & ~(size_t)255; return p; };

    __hip_bfloat16* W2 = (__hip_bfloat16*)alloc(szW2);
    __hip_bfloat16* Z  = (__hip_bfloat16*)alloc(szZ);
    __hip_bfloat16* XH = (__hip_bfloat16*)alloc(szXH);
    __hip_bfloat16* BM = (__hip_bfloat16*)alloc(szBM);
    __hip_bfloat16* CM = (__hip_bfloat16*)alloc(szCM);
    float* DT = (float*)alloc(szDT);
    float* LA = (float*)alloc(szLA);
    char*  R  = (char*)alloc(szR);
    __hip_bfloat16* A1  = (__hip_bfloat16*)R;
    __hip_bfloat16* W1  = (__hip_bfloat16*)(R + szA1);
    __hip_bfloat16* XBC = (__hip_bfloat16*)(R + szA1 + szW1);
    __hip_bfloat16* Yb = (__hip_bfloat16*)R;
    if (off > ws_size) return;   // clean fail instead of OOB crash

    // 1. converts (float4)
    int n1 = 2 * NPROJ * DMODEL / 4;
    cvt_kernel<<<(n1 + 255) / 256, 256, 0, stream>>>(in_w, W1, n1);
    int n2 = 2 * DMODEL * DINNER / 4;
    cvt_kernel<<<(n2 + 255) / 256, 256, 0, stream>>>(out_w, W2, n2);
    int n3 = 4096 * DMODEL / 4;
    cvt_kernel<<<(n3 + 255) / 256, 256, 0, stream>>>(x, A1, n3);

    // 2. in_proj GEMM: both dirs fused (z = dir), dir1 flips A rows in-gather
    {
        dim3 grid(4096 / 128, (NPROJ + 127) / 128, 2);
        gemm_bt<<<grid, 256, 0, stream>>>(A1, 0,
                                          W1, (size_t)NPROJ * DMODEL,
                                          nullptr, Z, XBC, DT, LA, dt_bias, A_log,
                                          4096, NPROJ, DMODEL, 1, 2, 1);
    }

    // 3. conv + silu
    conv_kernel<<<4 * 128, 256, 0, stream>>>(XBC, conv_w, conv_b, XH, BM, CM);

    // 4. fused SSD (Yb overlays A1/W1/XBC — all dead now)
    ssd_fused<<<4 * NH * 4, 256, 0, stream>>>(XH, BM, CM, DT, LA, Yb);

    // 5. gating + RMSNorm (A2 == Z, in-place)
    gate_kernel<<<2 * 4096, 192, 0, stream>>>(Yb, XH, Z, Dp, norm_w, Z);

    // 6. out_proj: zero-init + single launch (z = dir*2 + kslice), atomic adds, dir1 flips C rows
    hipMemsetAsync(out, 0, (size_t)4096 * DMODEL * 4, stream);
    {
        dim3 grid(4096 / 128, DMODEL / 128, 4);
        gemm_bt<<<grid, 256, 0, stream>>>(Z, (size_t)4096 * DINNER,
                                          W2, (size_t)DMODEL * DINNER,
                                          out, nullptr, nullptr, nullptr, nullptr, nullptr, nullptr,
                                          4096, DMODEL, DINNER, 2, 1, 0);
    }
}

// Round 13
// 384.164 us; speedup vs baseline: 1.3713x; 1.3713x over previous
//
#include <hip/hip_runtime.h>
#include <hip/hip_bf16.h>

typedef __attribute__((ext_vector_type(8))) short short8;
typedef __attribute__((ext_vector_type(4))) short bfx4;
typedef __attribute__((ext_vector_type(4))) float floatx4;

#define SEQ     2048
#define DMODEL  768
#define DINNER  1536
#define DSTATE  128
#define NH      24
#define CONVDIM 1792
#define NPROJ   3352   // 2*DINNER + 2*DSTATE + NH
#define QCH     64     // SSD chunk length
#define NCH     (SEQ / QCH)   // 32 chunks

__device__ inline float bf2f(short s) {
    return __uint_as_float(((unsigned)(unsigned short)s) << 16);
}
__device__ inline short f2bf(float f) {
    __hip_bfloat16 h = __float2bfloat16(f);
    return *reinterpret_cast<short*>(&h);
}
__device__ inline void gl_lds16(const void* g, void* l) {
    __builtin_amdgcn_global_load_lds((const __attribute__((address_space(1))) unsigned int*)g,
                                     (__attribute__((address_space(3))) unsigned int*)l, 16, 0, 0);
}

// ---------------------------------------------------------------- converts (float4)
__global__ __launch_bounds__(256) void cvt_kernel(const float* __restrict__ src,
                                                  __hip_bfloat16* __restrict__ dst, int n4) {
    int i = blockIdx.x * 256 + threadIdx.x;
    if (i >= n4) return;
    float4 v = *(const float4*)(src + (size_t)i * 4);
    bfx4 o = { f2bf(v.x), f2bf(v.y), f2bf(v.z), f2bf(v.w) };
    *(bfx4*)((short*)dst + (size_t)i * 4) = o;
}

// ---------------------------------------------------------------- GEMM 128x128, BK=32, double-buffered
// Packed row-pair LDS (8 KB/buf/matrix, bank-0-aligned lines, XOR slot map — 0 conflicts measured)
// blockIdx.z: dir = z/zdiv, kslice = z%zdiv. flipA: dir1 reads A rows flipped (shared A1).
// mode 1: out_proj atomic add (row flipped when dir==1); C pre-zeroed.
// mode 2: in_proj routing epilogue (per-dir output offsets).
__global__ __launch_bounds__(256) void gemm_bt(const __hip_bfloat16* __restrict__ Abase, size_t aStride,
                                               const __hip_bfloat16* __restrict__ Bbase, size_t bStride,
                                               float* __restrict__ C,
                                               __hip_bfloat16* __restrict__ Zb,
                                               __hip_bfloat16* __restrict__ Xb,
                                               float* __restrict__ DT,
                                               float* __restrict__ LA,
                                               const float* __restrict__ dtbias,
                                               const float* __restrict__ Alog,
                                               int M, int N, int K, int zdiv, int mode, int flipA) {
    __shared__ short As[2][64 * 64];   // 8 KB per buf: 64 lines x 128 B (rows l & l+64 packed)
    __shared__ short Bs[2][64 * 64];
    int tid = threadIdx.x;
    int w = tid >> 6, lane = tid & 63;
    int q = lane >> 4, mm = lane & 15;
    int wm = w >> 1, wn = w & 1;
    int m0 = blockIdx.x * 128, n0 = blockIdx.y * 128;
    int z = blockIdx.z;
    int dir = z / zdiv, ks = z - dir * zdiv;
    int kl = K / zdiv;
    int kbeg = ks * kl;
    const short* Ag = (const short*)Abase + (size_t)dir * aStride;
    const short* Bg = (const short*)Bbase + (size_t)dir * bStride;
    int fA = flipA && dir;

    // per-lane gather offsets for the 2 staging windows per wave (loop-invariant)
    size_t aoff[2], boff[2];
    int ldso[2];
#pragma unroll
    for (int j = 0; j < 2; j++) {
        int widx = w * 2 + j;            // 0..7 (8 windows x 8 lines = 64 lines)
        int ln = widx * 8 + (lane >> 3); // absolute line 0..63
        int s  = lane & 7;               // slot within line
        int c  = s ^ (ln & 7);
        int row = (c < 4) ? ln : ln + 64;
        int ch  = (c < 4) ? c : (c ^ 4);
        int ar = m0 + row;
        if (fA) { int bb = ar >> 11, tt = ar & 2047; ar = (bb << 11) + (2047 - tt); }
        aoff[j] = (size_t)ar * K + ch * 8;
        int br = n0 + row; if (br > N - 1) br = N - 1;   // dup rows; cols skipped on store
        boff[j] = (size_t)br * K + ch * 8;
        ldso[j] = widx * 1024;           // bytes
    }

    floatx4 acc[16];
#pragma unroll
    for (int i = 0; i < 16; i++) acc[i] = (floatx4){0.f, 0.f, 0.f, 0.f};

    int niter = kl / 32;
    auto stage = [&](int buf, int k0) {
#pragma unroll
        for (int j = 0; j < 2; j++) {
            gl_lds16(Ag + aoff[j] + kbeg + k0, (char*)&As[buf][0] + ldso[j]);
            gl_lds16(Bg + boff[j] + kbeg + k0, (char*)&Bs[buf][0] + ldso[j]);
        }
    };
    stage(0, 0);
    int slotA = (q ^ (mm & 7) ^ (wm << 2)) * 8;   // elements
    int slotB = (q ^ (mm & 7) ^ (wn << 2)) * 8;
    for (int it = 0; it < niter; it++) {
        __syncthreads();                           // buf[it&1] staged; prior reads done
        if (it + 1 < niter) stage((it + 1) & 1, (it + 1) * 32);
        const short* Ab = &As[it & 1][0];
        const short* Bb = &Bs[it & 1][0];
        short8 af[4], bfr[4];
#pragma unroll
        for (int mb = 0; mb < 4; mb++)
            af[mb] = *(const short8*)&Ab[(mb * 16 + mm) * 64 + slotA];
#pragma unroll
        for (int nb = 0; nb < 4; nb++)
            bfr[nb] = *(const short8*)&Bb[(nb * 16 + mm) * 64 + slotB];
#pragma unroll
        for (int mb = 0; mb < 4; mb++)
#pragma unroll
            for (int nb = 0; nb < 4; nb++)
                acc[mb * 4 + nb] = __builtin_amdgcn_mfma_f32_16x16x32_bf16(af[mb], bfr[nb], acc[mb * 4 + nb], 0, 0, 0);
    }

    __hip_bfloat16* Zb2 = Zb + (size_t)dir * 4096 * DINNER;
    __hip_bfloat16* Xb2 = Xb + (size_t)dir * 4096 * CONVDIM;
    float* DT2 = DT + (size_t)dir * 4096 * NH;
    float* LA2 = LA + (size_t)dir * 4096 * NH;
    const float* dtb2 = dtbias + dir * NH;
    const float* Al2  = Alog + dir * NH;

#pragma unroll
    for (int mb = 0; mb < 4; mb++) {
#pragma unroll
        for (int nb = 0; nb < 4; nb++) {
            int col = n0 + wn * 64 + nb * 16 + mm;
            if (col >= N) continue;
#pragma unroll
            for (int r = 0; r < 4; r++) {
                int rr = m0 + wm * 64 + mb * 16 + q * 4 + r;
                float v = acc[mb * 4 + nb][r];
                if (mode == 1) {
                    int orow = rr;
                    if (dir) { int b = rr >> 11, t = rr & 2047; orow = (b << 11) + (2047 - t); }
                    atomicAdd(&C[(size_t)orow * N + col], v);
                } else {
                    if (col < DINNER) {
                        Zb2[(size_t)rr * DINNER + col] = __float2bfloat16(v);
                    } else if (col < DINNER + CONVDIM) {
                        Xb2[(size_t)rr * CONVDIM + (col - DINNER)] = __float2bfloat16(v);
                    } else {
                        int hh = col - (DINNER + CONVDIM);
                        float raw = v + dtb2[hh];
                        float dtv = (raw > 20.f) ? raw : log1pf(__expf(raw));
                        float Av  = -__expf(Al2[hh]);
                        DT2[(size_t)rr * NH + hh] = dtv;
                        LA2[(size_t)rr * NH + hh] = dtv * Av;
                    }
                }
            }
        }
    }
}

// ---------------------------------------------------------------- conv (depthwise K=4) + silu
__global__ __launch_bounds__(256) void conv_kernel(const __hip_bfloat16* __restrict__ Xb,
                                                   const float* __restrict__ conv_w,
                                                   const float* __restrict__ conv_b,
                                                   __hip_bfloat16* __restrict__ xh,
                                                   __hip_bfloat16* __restrict__ Bm,
                                                   __hip_bfloat16* __restrict__ Cm) {
    int db  = blockIdx.x >> 7;
    int dir = db >> 1;
    int t0  = (blockIdx.x & 127) * 16;
    int c8  = threadIdx.x * 8;
    if (c8 >= CONVDIM) return;

    float wk[4][8], bs[8];
#pragma unroll
    for (int j = 0; j < 8; j++) {
        bs[j] = conv_b[dir * CONVDIM + c8 + j];
#pragma unroll
        for (int k = 0; k < 4; k++) wk[k][j] = conv_w[((size_t)dir * CONVDIM + c8 + j) * 4 + k];
    }

    const short* xrow = (const short*)Xb + (size_t)db * SEQ * CONVDIM + c8;
    short8 win[4];
    const short8 zer = {0, 0, 0, 0, 0, 0, 0, 0};
#pragma unroll
    for (int k = 0; k < 3; k++) {
        int ts = t0 - 3 + k;
        win[k] = (ts >= 0) ? *(const short8*)(xrow + (size_t)ts * CONVDIM) : zer;
    }

    for (int tt = 0; tt < 16; tt++) {
        int t = t0 + tt;
        win[3] = *(const short8*)(xrow + (size_t)t * CONVDIM);
        short8 outv;
#pragma unroll
        for (int j = 0; j < 8; j++) {
            float acc = bs[j];
#pragma unroll
            for (int k = 0; k < 4; k++) acc += wk[k][j] * bf2f(win[k][j]);
            float sv = acc / (1.f + __expf(-acc));
            outv[j] = f2bf(sv);
        }
        if (c8 < DINNER)
            *(short8*)((short*)xh + (size_t)(db * SEQ + t) * DINNER + c8) = outv;
        else if (c8 < DINNER + DSTATE)
            *(short8*)((short*)Bm + (size_t)(db * SEQ + t) * DSTATE + (c8 - DINNER)) = outv;
        else
            *(short8*)((short*)Cm + (size_t)(db * SEQ + t) * DSTATE + (c8 - DINNER - DSTATE)) = outv;
        win[0] = win[1]; win[1] = win[2]; win[2] = win[3];
    }
}

// ---------------------------------------------------------------- SSD pass 1
__global__ __launch_bounds__(256) void ssd1_kernel(const __hip_bfloat16* __restrict__ XH,
                                                   const __hip_bfloat16* __restrict__ BMh,
                                                   const float* __restrict__ DT,
                                                   const float* __restrict__ LA,
                                                   short* __restrict__ SS,
                                                   float* __restrict__ CUM) {
    int blk = blockIdx.x;
    int ck = blk & 31;
    int dbh = blk >> 5;
    int hh = dbh % NH, db = dbh / NH;
    int base_row = db * SEQ + ck * QCH;

    __shared__ float cum_s[QCH], dt_s[QCH];
    __shared__ short Xt[64][72];
    __shared__ short Bt[128][72];

    int tid = threadIdx.x;
    int lane = tid & 63, w = tid >> 6;
    int q = lane >> 4, mm = lane & 15;

    if (tid < QCH) {
        float la  = LA[(size_t)(base_row + tid) * NH + hh];
        float dtv = DT[(size_t)(base_row + tid) * NH + hh];
        float cs = la;
#pragma unroll
        for (int d = 1; d < 64; d <<= 1) {
            float u = __shfl_up(cs, d);
            if (tid >= d) cs += u;
        }
        cum_s[tid] = cs;
        dt_s[tid] = dtv;
        CUM[(size_t)dbh * SEQ + ck * QCH + tid] = cs;
    }
    __syncthreads();
    float cumL = cum_s[QCH - 1];

    {
        int s2 = (tid & 31) * 2, pb = tid >> 5;
        float f0 = dt_s[s2]     * __expf(cumL - cum_s[s2]);
        float f1 = dt_s[s2 + 1] * __expf(cumL - cum_s[s2 + 1]);
        const short* r0 = (const short*)XH + (size_t)(base_row + s2) * DINNER + hh * 64 + pb * 8;
        const short* r1 = r0 + DINNER;
        short8 x0 = *(const short8*)r0;
        short8 x1 = *(const short8*)r1;
#pragma unroll
        for (int j = 0; j < 8; j++) {
            unsigned lo = (unsigned short)f2bf(f0 * bf2f(x0[j]));
            unsigned hi = (unsigned short)f2bf(f1 * bf2f(x1[j]));
            *(unsigned*)&Xt[pb * 8 + j][s2] = lo | (hi << 16);
        }
    }
    {
        int s2 = (tid & 31) * 2, nb = tid >> 5;
        const short* r0 = (const short*)BMh + (size_t)(base_row + s2) * DSTATE + nb * 16;
        const short* r1 = r0 + DSTATE;
        short8 b0a = *(const short8*)r0,  b0b = *(const short8*)(r0 + 8);
        short8 b1a = *(const short8*)r1,  b1b = *(const short8*)(r1 + 8);
#pragma unroll
        for (int j = 0; j < 8; j++) {
            *(unsigned*)&Bt[nb * 16 + j][s2] =
                (unsigned)(unsigned short)b0a[j] | ((unsigned)(unsigned short)b1a[j] << 16);
            *(unsigned*)&Bt[nb * 16 + 8 + j][s2] =
                (unsigned)(unsigned short)b0b[j] | ((unsigned)(unsigned short)b1b[j] << 16);
        }
    }
    __syncthreads();

    floatx4 acc[8];
#pragma unroll
    for (int i = 0; i < 8; i++) acc[i] = (floatx4){0.f, 0.f, 0.f, 0.f};
#pragma unroll
    for (int kk = 0; kk < 2; kk++) {
        short8 a = *(const short8*)&Xt[w * 16 + mm][kk * 32 + q * 8];
#pragma unroll
        for (int cb = 0; cb < 8; cb++) {
            short8 b = *(const short8*)&Bt[cb * 16 + mm][kk * 32 + q * 8];
            acc[cb] = __builtin_amdgcn_mfma_f32_16x16x32_bf16(a, b, acc[cb], 0, 0, 0);
        }
    }
    short* Sp = SS + (size_t)blk * 8192;
#pragma unroll
    for (int cb = 0; cb < 8; cb++)
#pragma unroll
        for (int r = 0; r < 4; r++)
            Sp[(w * 16 + q * 4 + r) * DSTATE + cb * 16 + mm] = f2bf(acc[cb][r]);
}

// ---------------------------------------------------------------- SSD pass 2: inter-chunk scan
__global__ __launch_bounds__(256) void ssd2_kernel(const short* __restrict__ SS,
                                                   const float* __restrict__ CUM,
                                                   short* __restrict__ Hprev) {
    int blk = blockIdx.x;
    int dbh = blk >> 2, part = blk & 3;
    int off = part * 2048 + threadIdx.x * 8;
    size_t base = (size_t)dbh * NCH * 8192 + off;
    float h[8];
#pragma unroll
    for (int j = 0; j < 8; j++) h[j] = 0.f;
    for (int c = 0; c < NCH; c++) {
        float W = __expf(CUM[(size_t)dbh * SEQ + c * QCH + QCH - 1]);
        size_t p = base + (size_t)c * 8192;
        short8 s = *(const short8*)(SS + p);
        short8 o;
#pragma unroll
        for (int j = 0; j < 8; j++) o[j] = f2bf(h[j]);
        *(short8*)(Hprev + p) = o;
#pragma unroll
        for (int j = 0; j < 8; j++) h[j] = fmaf(h[j], W, bf2f(s[j]));
    }
}

// ---------------------------------------------------------------- SSD pass 3
__global__ __launch_bounds__(256) void ssd3_kernel(const __hip_bfloat16* __restrict__ XH,
                                                   const __hip_bfloat16* __restrict__ BMh,
                                                   const __hip_bfloat16* __restrict__ CMh,
                                                   const float* __restrict__ DT,
                                                   const float* __restrict__ CUM,
                                                   const short* __restrict__ Hprev,
                                                   __hip_bfloat16* __restrict__ Yb) {
    int blk = blockIdx.x;
    int ck = blk & 31;
    int dbh = blk >> 5;
    int hh = dbh % NH, db = dbh / NH;
    int base_row = db * SEQ + ck * QCH;

    __shared__ float cum_s[QCH], dt_s[QCH];
    __shared__ short Ct[64][136];
    __shared__ short G[64][72];
    __shared__ short Xt[64][72];

    int tid = threadIdx.x;
    int lane = tid & 63, w = tid >> 6;
    int q = lane >> 4, mm = lane & 15;

    if (tid < QCH) {
        cum_s[tid] = CUM[(size_t)dbh * SEQ + ck * QCH + tid];
        dt_s[tid]  = DT[(size_t)(base_row + tid) * NH + hh];
    }

    const short* Cg = (const short*)CMh + (size_t)base_row * DSTATE;
    const short* Bg = (const short*)BMh + (size_t)base_row * DSTATE;
    floatx4 P[4];
#pragma unroll
    for (int i = 0; i < 4; i++) P[i] = (floatx4){0.f, 0.f, 0.f, 0.f};
#pragma unroll
    for (int kk = 0; kk < 4; kk++) {
        short8 a = *(const short8*)(Cg + (size_t)(w * 16 + mm) * DSTATE + kk * 32 + q * 8);
#pragma unroll
        for (int cb = 0; cb < 4; cb++) {
            short8 b = *(const short8*)(Bg + (size_t)(cb * 16 + mm) * DSTATE + kk * 32 + q * 8);
            P[cb] = __builtin_amdgcn_mfma_f32_16x16x32_bf16(a, b, P[cb], 0, 0, 0);
        }
    }
    __syncthreads();

    {
        int t = tid & 63, nb4 = tid >> 6;
        float wt = __expf(cum_s[t]);
        const short* src = Cg + (size_t)t * DSTATE + nb4 * 32;
#pragma unroll
        for (int u = 0; u < 2; u++) {
            short8 v = *(const short8*)(src + u * 16);
            short8 v2 = *(const short8*)(src + u * 16 + 8);
#pragma unroll
            for (int j = 0; j < 4; j++) {
                unsigned lo = (unsigned short)f2bf(wt * bf2f(v[2 * j]));
                unsigned hi = (unsigned short)f2bf(wt * bf2f(v[2 * j + 1]));
                *(unsigned*)&Ct[t][nb4 * 32 + u * 16 + 2 * j] = lo | (hi << 16);
                lo = (unsigned short)f2bf(wt * bf2f(v2[2 * j]));
                hi = (unsigned short)f2bf(wt * bf2f(v2[2 * j + 1]));
                *(unsigned*)&Ct[t][nb4 * 32 + u * 16 + 8 + 2 * j] = lo | (hi << 16);
            }
        }
    }
    {
        int s2 = (tid & 31) * 2, pb = tid >> 5;
        const short* r0 = (const short*)XH + (size_t)(base_row + s2) * DINNER + hh * 64 + pb * 8;
        const short* r1 = r0 + DINNER;
        short8 x0 = *(const short8*)r0;
        short8 x1 = *(const short8*)r1;
#pragma unroll
        for (int j = 0; j < 8; j++) {
            *(unsigned*)&Xt[pb * 8 + j][s2] =
                (unsigned)(unsigned short)x0[j] | ((unsigned)(unsigned short)x1[j] << 16);
        }
    }
#pragma unroll
    for (int cb = 0; cb < 4; cb++) {
#pragma unroll
        for (int r = 0; r < 4; r++) {
            int t = w * 16 + q * 4 + r;
            int s = cb * 16 + mm;
            float g = (s <= t) ? P[cb][r] * __expf(cum_s[t] - cum_s[s]) * dt_s[s] : 0.f;
            G[t][s] = f2bf(g);
        }
    }
    __syncthreads();

    floatx4 Y[4];
#pragma unroll
    for (int i = 0; i < 4; i++) Y[i] = (floatx4){0.f, 0.f, 0.f, 0.f};
#pragma unroll
    for (int kk = 0; kk < 2; kk++) {
        short8 a = *(const short8*)&G[w * 16 + mm][kk * 32 + q * 8];
#pragma unroll
        for (int cb = 0; cb < 4; cb++) {
            short8 b = *(const short8*)&Xt[cb * 16 + mm][kk * 32 + q * 8];
            Y[cb] = __builtin_amdgcn_mfma_f32_16x16x32_bf16(a, b, Y[cb], 0, 0, 0);
        }
    }
    const short* Hc = Hprev + (size_t)blk * 8192;
#pragma unroll
    for (int kk = 0; kk < 4; kk++) {
        short8 a = *(const short8*)&Ct[w * 16 + mm][kk * 32 + q * 8];
#pragma unroll
        for (int cb = 0; cb < 4; cb++) {
            short8 b = *(const short8*)(Hc + (size_t)(cb * 16 + mm) * DSTATE + kk * 32 + q * 8);
            Y[cb] = __builtin_amdgcn_mfma_f32_16x16x32_bf16(a, b, Y[cb], 0, 0, 0);
        }
    }
#pragma unroll
    for (int cb = 0; cb < 4; cb++)
#pragma unroll
        for (int r = 0; r < 4; r++)
            Yb[(size_t)(base_row + w * 16 + q * 4 + r) * DINNER + hh * 64 + cb * 16 + mm] =
                __float2bfloat16(Y[cb][r]);
}

// ---------------------------------------------------------------- gating + RMSNorm (192 thr x 8 ch)
__global__ __launch_bounds__(192) void gate_kernel(const __hip_bfloat16* __restrict__ Yb,
                                                   const __hip_bfloat16* __restrict__ xh,
                                                   const __hip_bfloat16* __restrict__ Zb,
                                                   const float* __restrict__ Dp,
                                                   const float* __restrict__ norm_w,
                                                   __hip_bfloat16* __restrict__ A2) {
    int row = blockIdx.x;
    int dir = row >> 12;
    int c8 = threadIdx.x * 8;
    int hd = c8 >> 6;
    const short* yr = (const short*)Yb + (size_t)row * DINNER + c8;
    const short* xr = (const short*)xh + (size_t)row * DINNER + c8;
    const short* zr = (const short*)Zb + (size_t)row * DINNER + c8;

    short8 y8 = *(const short8*)yr;
    short8 x8 = *(const short8*)xr;
    short8 z8 = *(const short8*)zr;
    float Dv = Dp[dir * NH + hd];

    float vals[8];
    float ss = 0.f;
#pragma unroll
    for (int j = 0; j < 8; j++) {
        float v = bf2f(y8[j]) + Dv * bf2f(x8[j]);
        float z = bf2f(z8[j]);
        v *= z / (1.f + __expf(-z));
        vals[j] = v;
        ss += v * v;
    }
#pragma unroll
    for (int off = 32; off; off >>= 1) ss += __shfl_down(ss, off);
    __shared__ float ls[3];
    if ((threadIdx.x & 63) == 0) ls[threadIdx.x >> 6] = ss;
    __syncthreads();
    float tot = ls[0] + ls[1] + ls[2];
    float scale = rsqrtf(tot / (float)DINNER + 1e-5f);

    const float* nw = norm_w + dir * DINNER + c8;
    short8 o;
#pragma unroll
    for (int j = 0; j < 8; j++) o[j] = f2bf(vals[j] * scale * nw[j]);
    *(short8*)((short*)A2 + (size_t)row * DINNER + c8) = o;
}

// ---------------------------------------------------------------- launch
extern "C" void kernel_launch(void* const* d_in, const int* in_sizes, int n_in,
                              void* d_out, int out_size, void* d_ws, size_t ws_size,
                              hipStream_t stream) {
    const float* x        = (const float*)d_in[0];
    const float* in_w     = (const float*)d_in[1];
    const float* conv_w   = (const float*)d_in[2];
    const float* conv_b   = (const float*)d_in[3];
    const float* dt_bias  = (const float*)d_in[4];
    const float* A_log    = (const float*)d_in[5];
    const float* Dp       = (const float*)d_in[6];
    const float* norm_w   = (const float*)d_in[7];
    const float* out_w    = (const float*)d_in[8];
    float* out = (float*)d_out;

    const size_t szW2 = (size_t)2 * DMODEL * DINNER * 2;
    const size_t szZ  = (size_t)8192 * DINNER * 2;
    const size_t szXH = (size_t)8192 * DINNER * 2;
    const size_t szBM = (size_t)8192 * DSTATE * 2;
    const size_t szCM = szBM;
    const size_t szDT = (size_t)8192 * NH * 4;
    const size_t szLA = szDT;
    const size_t szA1 = (size_t)4096 * DMODEL * 2;     // unflipped, shared by both dirs
    const size_t szW1 = (size_t)2 * NPROJ * DMODEL * 2;
    const size_t szXB = (size_t)8192 * CONVDIM * 2;
    const size_t szYb = (size_t)8192 * DINNER * 2;
    const size_t szSS = (size_t)96 * NCH * 8192 * 2;
    const size_t szRa = szA1 + szW1 + szXB;
    size_t szR = szRa;
    if (szR < szYb) szR = szYb;
    if (szR < szSS) szR = szSS;
    const size_t szHp = szSS;
    const size_t szCU = (size_t)96 * SEQ * 4;

    char* ws = (char*)d_ws;
    size_t off = 0;
    auto alloc = [&](size_t bytes) { char* p = ws + off; off += (bytes + 255) & ~(size_t)255; return p; };

    __hip_bfloat16* W2 = (__hip_bfloat16*)alloc(szW2);
    __hip_bfloat16* Z  = (__hip_bfloat16*)alloc(szZ);
    __hip_bfloat16* XH = (__hip_bfloat16*)alloc(szXH);
    __hip_bfloat16* BM = (__hip_bfloat16*)alloc(szBM);
    __hip_bfloat16* CM = (__hip_bfloat16*)alloc(szCM);
    float* DT = (float*)alloc(szDT);
    float* LA = (float*)alloc(szLA);
    char*  R  = (char*)alloc(szR);
    __hip_bfloat16* A1  = (__hip_bfloat16*)R;
    __hip_bfloat16* W1  = (__hip_bfloat16*)(R + szA1);
    __hip_bfloat16* XBC = (__hip_bfloat16*)(R + szA1 + szW1);
    short* SS = (short*)R;
    __hip_bfloat16* Yb = (__hip_bfloat16*)R;

    short* Hp = (short*)alloc(szHp);
    float* CU = (float*)alloc(szCU);
    if (off > ws_size) return;   // clean fail instead of OOB crash

    // 1. converts (float4): weights + x (A1 rows = b*SEQ+t, unflipped)
    int n1 = 2 * NPROJ * DMODEL / 4;
    cvt_kernel<<<(n1 + 255) / 256, 256, 0, stream>>>(in_w, W1, n1);
    int n2 = 2 * DMODEL * DINNER / 4;
    cvt_kernel<<<(n2 + 255) / 256, 256, 0, stream>>>(out_w, W2, n2);
    int n3 = 4096 * DMODEL / 4;
    cvt_kernel<<<(n3 + 255) / 256, 256, 0, stream>>>(x, A1, n3);

    // 2. in_proj GEMM: both dirs fused (z = dir), dir1 flips A rows in-gather
    {
        dim3 grid(4096 / 128, (NPROJ + 127) / 128, 2);
        gemm_bt<<<grid, 256, 0, stream>>>(A1, 0,
                                          W1, (size_t)NPROJ * DMODEL,
                                          nullptr, Z, XBC, DT, LA, dt_bias, A_log,
                                          4096, NPROJ, DMODEL, 1, 2, 1);
    }

    // 3. conv + silu
    conv_kernel<<<4 * 128, 256, 0, stream>>>(XBC, conv_w, conv_b, XH, BM, CM);

    // 4. SSD chunked scan (3-pass)
    ssd1_kernel<<<4 * NH * NCH, 256, 0, stream>>>(XH, BM, DT, LA, SS, CU);
    ssd2_kernel<<<4 * NH * 4, 256, 0, stream>>>(SS, CU, Hp);
    ssd3_kernel<<<4 * NH * NCH, 256, 0, stream>>>(XH, BM, CM, DT, CU, Hp, Yb);

    // 5. gating + RMSNorm (A2 == Z, in-place)
    gate_kernel<<<2 * 4096, 192, 0, stream>>>(Yb, XH, Z, Dp, norm_w, Z);

    // 6. out_proj: zero-init + single launch (z = dir*2 + kslice), atomic adds, dir1 flips C rows
    hipMemsetAsync(out, 0, (size_t)4096 * DMODEL * 4, stream);
    {
        dim3 grid(4096 / 128, DMODEL / 128, 4);
        gemm_bt<<<grid, 256, 0, stream>>>(Z, (size_t)4096 * DINNER,
                                          W2, (size_t)DMODEL * DINNER,
                                          out, nullptr, nullptr, nullptr, nullptr, nullptr, nullptr,
                                          4096, DMODEL, DINNER, 2, 1, 0);
    }
}